// Round 2
// baseline (78.519 us; speedup 1.0000x reference)
//
#include <hip/hip_runtime.h>
#include <stdint.h>

// Bit-serial conv2d closed form: term = sign(w) * ((x * |w|) >> 4)
//                                     = (x * w + A) >> 4   [arith shift]
// where A = (w<0) ? 15 : 0.  x in [0,15], w in [-8,7].
// out = relu(bias + sum_{3x3,c} term).  B=4 H=32 W=32 C=64 F=128.
// Exact in i16 (per packed half |acc| <= 7*72 = 504).
//
// Single fused kernel: weights converted f32->packed i16 inline (each weight
// used once per thread; no ws round-trip, no prep dispatch, d_ws unused).
// x staged raw->packed in LDS with fused 'same' padding; each x int4 loaded
// once per (row,g) and reused across the 3 horizontal kernel positions.

typedef short s16x2 __attribute__((ext_vector_type(2)));

// 512 blocks x 512 threads, single fully-resident round (2 blocks/CU).
// Block = (b, h, wq): 8 output cols x 128 f.  Thread (cq = tid>>7, f = tid&127):
// 16-channel slice, 8 pixel partials, LDS reduce over cq.
__global__ __launch_bounds__(512, 4) void conv_fused(const float* __restrict__ kern,
                                                     const float* __restrict__ input,
                                                     const float* __restrict__ bias,
                                                     float* __restrict__ out) {
    int bid = blockIdx.x;
    int wq  = bid & 3;
    int h   = (bid >> 2) & 31;
    int b   = bid >> 7;
    int tid = threadIdx.x;
    int f   = tid & 127;
    int cq  = tid >> 7;          // wave-uniform
    int w0  = wq * 8;

    __shared__ uint32_t xl[3 * 10 * 32];   // [row][col 0..9][c2]  3.75 KB
    __shared__ int prt[4 * 8 * 128];       // partial [cq][px][f]  16 KB

    // stage x-patch: 3 rows x 10 cols x 64 ch raw floats -> packed i16 pairs.
    // 480 float4 loads (16 consecutive per (row,col) segment -> coalesced).
    if (tid < 480) {
        int q   = tid & 15;                // float4 index within 64 channels
        int rc  = tid >> 4;                // [0,30): r*10 + col
        int col = rc % 10;
        int r   = rc / 10;
        int hp  = h + r - 1;
        int wp  = w0 + col - 1;
        int2 v2 = {0, 0};
        if (hp >= 0 && hp < 32 && wp >= 0 && wp < 32) {
            const float4 v = *(const float4*)&input[(((b * 32) + hp) * 32 + wp) * 64 + q * 4];
            v2.x = (int)v.x | ((int)v.y << 16);
            v2.y = (int)v.z | ((int)v.w << 16);
        }
        *(int2*)&xl[rc * 32 + q * 2] = v2;
    }

    int bv = (int)bias[f];                       // hoisted before barrier
    // weight c-slice base for this thread: kern[ki][cq*16 + c_local][f]
    const float* wbase = kern + (cq * 16) * 128 + f;

    __syncthreads();

    s16x2 acc[8];
    #pragma unroll
    for (int i = 0; i < 8; ++i) acc[i] = (s16x2){0, 0};

    #pragma unroll
    for (int r = 0; r < 3; ++r) {
        #pragma unroll
        for (int g = 0; g < 2; ++g) {
            // load the 10 x-columns for this (row, g) ONCE (broadcast reads,
            // wave-uniform addr), reuse across jj = 0..2
            int4 xv[10];
            const uint32_t* xrow = xl + r * 10 * 32 + cq * 8 + g * 4;
            #pragma unroll
            for (int col = 0; col < 10; ++col)
                xv[col] = *(const int4*)(xrow + col * 32);   // ds_read_b128
            #pragma unroll
            for (int jj = 0; jj < 3; ++jj) {
                int ki = r * 3 + jj;
                // inline weight pack: 8 raw f32 (lane-coalesced over f) -> 4 s16x2
                s16x2 wv[4], Av[4];
                #pragma unroll
                for (int u = 0; u < 4; ++u) {
                    int c = g * 8 + u * 2;
                    int wlo = (int)wbase[(ki * 64 + c    ) * 128];
                    int whi = (int)wbase[(ki * 64 + c + 1) * 128];
                    uint32_t wpk = (uint32_t)(uint16_t)(int16_t)wlo |
                                   ((uint32_t)(uint16_t)(int16_t)whi << 16);
                    wv[u] = __builtin_bit_cast(s16x2, wpk);
                    Av[u] = (wv[u] >> 15) & (short)15;       // 15 where w<0
                }
                #pragma unroll
                for (int u = 0; u < 4; ++u) {
                    #pragma unroll
                    for (int px = 0; px < 8; ++px) {
                        s16x2 xs = __builtin_bit_cast(s16x2, (&xv[jj + px].x)[u]);
                        acc[px] += (xs * wv[u] + Av[u]) >> 4;  // pk_mad/shr/add
                    }
                }
            }
        }
    }

    // per-thread horizontal add (2 channel halves), stash partials
    #pragma unroll
    for (int px = 0; px < 8; ++px) {
        int a = __builtin_bit_cast(int, acc[px]);
        prt[(cq * 8 + px) * 128 + f] = (int)(short)(a & 0xffff) + (a >> 16);
    }
    __syncthreads();

    // reduce 4 c-quarters, bias, relu, store: 1024 outputs / 512 threads
    #pragma unroll
    for (int k = 0; k < 2; ++k) {
        int px = (tid >> 7) + k * 4;
        int v = prt[(0 * 8 + px) * 128 + f] + prt[(1 * 8 + px) * 128 + f] +
                prt[(2 * 8 + px) * 128 + f] + prt[(3 * 8 + px) * 128 + f] + bv;
        out[((b * 32 + h) * 32 + w0 + px) * 128 + f] = (float)(v < 0 ? 0 : v);
    }
}

extern "C" void kernel_launch(void* const* d_in, const int* in_sizes, int n_in,
                              void* d_out, int out_size, void* d_ws, size_t ws_size,
                              hipStream_t stream) {
    const float* input  = (const float*)d_in[0];   // [4,32,32,64]
    const float* kernel = (const float*)d_in[1];   // [3,3,64,128]
    const float* bias   = (const float*)d_in[2];   // [128]
    // d_in[3] = bits (==4, baked into the closed form); d_ws unused

    conv_fused<<<512, 512, 0, stream>>>(kernel, input, bias, (float*)d_out);
}